// Round 4
// baseline (96.787 us; speedup 1.0000x reference)
//
#include <hip/hip_runtime.h>
#include <hip/hip_bf16.h>
#include <stdint.h>

#define BB   8
#define LL   1024
#define LOO  1024
#define HH   768
#define VV   4096
#define OUTW 5120   // VV + LL
#define EMAX 256    // tags sorted from [0,256) => emitted <= 255

typedef unsigned short ushort_t;
typedef __attribute__((ext_vector_type(4))) float   f32x4;
typedef __attribute__((ext_vector_type(8))) __bf16  bf16x8;
typedef __attribute__((ext_vector_type(4))) float   float4v;
typedef __attribute__((ext_vector_type(4))) int     int4v;

static __device__ __forceinline__ ushort_t f2bf(float f) {
    union { float f; uint32_t u; } v; v.f = f;
    uint32_t u = v.u;
    uint32_t r = (u + 0x7fffu + ((u >> 16) & 1u)) >> 16;
    return (ushort_t)r;
}

// ---- K1: fused tag-scan + segment means -> bf16 attn [BB][EMAX][HH] ----
__global__ __launch_bounds__(256) void attn_fused_kernel(
        const float* __restrict__ h1,
        const int* __restrict__ tags,
        ushort_t* __restrict__ attn,
        int* __restrict__ emitted_out) {
    int b = blockIdx.x >> 8;
    int r = blockIdx.x & 255;
    int tid = threadIdx.x;

    __shared__ int stags[LL];        // 4 KB
    __shared__ int cnt[256];
    __shared__ int runpos[EMAX + 2];

    ((int4v*)stags)[tid] = ((const int4v*)(tags + b * LL))[tid];
    __syncthreads();

    int p0 = tid * 4;
    int st[4];
    int prevm1 = (p0 == 0) ? -2 : stags[p0 - 1];
    st[0] = (p0 == 0) || (stags[p0] != prevm1);
    st[1] = (stags[p0 + 1] != stags[p0]);
    st[2] = (stags[p0 + 2] != stags[p0 + 1]);
    st[3] = (stags[p0 + 3] != stags[p0 + 2]);
    int c = st[0] + st[1] + st[2] + st[3];
    cnt[tid] = c;
    __syncthreads();
    for (int off = 1; off < 256; off <<= 1) {
        int v = cnt[tid];
        int a = (tid >= off) ? cnt[tid - off] : 0;
        __syncthreads();
        cnt[tid] = v + a;
        __syncthreads();
    }
    int total = cnt[255];            // total runs (<= 256, tags sorted)
    int base = cnt[tid] - c;         // exclusive prefix
#pragma unroll
    for (int j = 0; j < 4; ++j)
        if (st[j]) runpos[base++] = p0 + j;
    if (tid == 0) runpos[total] = LL;
    __syncthreads();

    int em = total - 1;              // trailing open run dropped
    if (r == 0 && tid == 0) emitted_out[b] = em;

    ushort_t* arow = attn + ((size_t)b * EMAX + r) * HH;
    if (r >= em) {
        arow[tid] = 0; arow[tid + 256] = 0; arow[tid + 512] = 0;
        return;
    }
    int s = runpos[r], e = runpos[r + 1];
    float inv = 1.0f / (float)(e - s);
    const float* hb = h1 + (size_t)b * LL * HH;
    float a0 = 0.f, a1 = 0.f, a2 = 0.f;
    for (int p = s; p < e; ++p) {
        const float* row = hb + (size_t)p * HH;
        a0 += row[tid]; a1 += row[tid + 256]; a2 += row[tid + 512];
    }
    arow[tid]       = f2bf(a0 * inv);
    arow[tid + 256] = f2bf(a1 * inv);
    arow[tid + 512] = f2bf(a2 * inv);
}

// ------------- K2 mega: GEMM blocks + copy/fill blocks, ZERO LDS -------------
// Blocks [0,256): batched NT GEMM over out cols [VV, VV+256). Tile 128x64,
//   4 waves (2Mx2N), per-wave 64x32. A (f32) and B (bf16) fragments are read
//   directly global->register (operands are L2/L3-hot; no LDS, no barriers).
// Blocks [256, 256+2048): copy lm_logits into out[:,:,0:VV] and fill
//   out[:,:,VV+256..VV+LL) with -100.
#define NGEMM 256
#define NCOPY 2048
__global__ __launch_bounds__(256, 4) void mega_kernel(
        const float* __restrict__ A,       // h2 f32 [BB][LOO][HH]
        const ushort_t* __restrict__ Bm,   // attn bf16 [BB][EMAX][HH]
        const int* __restrict__ emitted,
        const float* __restrict__ lm,
        float* __restrict__ out) {

    if (blockIdx.x >= NGEMM) {
        // ---------------- copy + fill path ----------------
        int cid = blockIdx.x - NGEMM;     // 0..2047
        int tid = threadIdx.x;
        const float4v* in4 = (const float4v*)lm;
        float4v* out4 = (float4v*)out;
        int c = cid * 256 + tid;          // 0..524287
#pragma unroll
        for (int g = 0; g < 4; ++g) {
            size_t i0 = (size_t)(g * 4 + 0) * 524288 + c;
            size_t i1 = (size_t)(g * 4 + 1) * 524288 + c;
            size_t i2 = (size_t)(g * 4 + 2) * 524288 + c;
            size_t i3 = (size_t)(g * 4 + 3) * 524288 + c;
            float4v v0 = in4[i0];
            float4v v1 = in4[i1];
            float4v v2 = in4[i2];
            float4v v3 = in4[i3];
            out4[i0 + ((i0 >> 10) << 8)] = v0;   // out_idx = i + row*256
            out4[i1 + ((i1 >> 10) << 8)] = v1;
            out4[i2 + ((i2 >> 10) << 8)] = v2;
            out4[i3 + ((i3 >> 10) << 8)] = v3;
        }
        // fill out cols [VV+256, VV+1024): 192 float4/row, 4 rows/block
        float4v fv = {-100.f, -100.f, -100.f, -100.f};
        if (tid < 192) {
#pragma unroll
            for (int j = 0; j < 4; ++j) {
                size_t row = (size_t)cid * 4 + j;      // 0..8191
                out4[row * (OUTW / 4) + (VV + 256) / 4 + tid] = fv;
            }
        }
        return;
    }

    // ---------------- GEMM path (no LDS, no barriers) ----------------
    int bid  = blockIdx.x;
    int b    = bid >> 5;                  // 32 tiles per batch
    int t2   = bid & 31;
    int brow = (t2 >> 2) << 7;            // 8 row-tiles * 128
    int bcol = (t2 & 3) << 6;             // 4 col-tiles * 64

    const int tid  = threadIdx.x;
    const int lane = tid & 63;
    const int wid  = tid >> 6;
    const int wr   = (wid >> 1) & 1;      // M half
    const int wc   = wid & 1;             // N half

    const float*    Ab = A  + (size_t)b * LOO * HH;
    const ushort_t* Bb = Bm + (size_t)b * EMAX * HH;

    // per-lane fragment bases (16x16x32 bf16 MFMA: row=lane&15, k=(lane>>4)*8)
    const int arow0 = brow + (wr << 6) + (lane & 15);
    const int brow0 = bcol + (wc << 5) + (lane & 15);
    const int ksub  = (lane >> 4) << 3;           // k sub-offset 0,8,16,24

    f32x4 zero = {0.f, 0.f, 0.f, 0.f};
    f32x4 acc[4][2];
#pragma unroll
    for (int i = 0; i < 4; ++i) { acc[i][0] = zero; acc[i][1] = zero; }

#pragma unroll 2
    for (int k0 = 0; k0 < HH; k0 += 32) {
        bf16x8 af[4], bfr[2];
#pragma unroll
        for (int mi = 0; mi < 4; ++mi) {
            const float* pa = Ab + (size_t)(arow0 + (mi << 4)) * HH + k0 + ksub;
            f32x4 a0 = *(const f32x4*)pa;
            f32x4 a1 = *(const f32x4*)(pa + 4);
            bf16x8 t;
            t[0] = (__bf16)a0[0]; t[1] = (__bf16)a0[1];
            t[2] = (__bf16)a0[2]; t[3] = (__bf16)a0[3];
            t[4] = (__bf16)a1[0]; t[5] = (__bf16)a1[1];
            t[6] = (__bf16)a1[2]; t[7] = (__bf16)a1[3];
            af[mi] = t;
        }
#pragma unroll
        for (int ni = 0; ni < 2; ++ni)
            bfr[ni] = *(const bf16x8*)(Bb + (size_t)(brow0 + (ni << 4)) * HH + k0 + ksub);
#pragma unroll
        for (int mi = 0; mi < 4; ++mi)
#pragma unroll
            for (int ni = 0; ni < 2; ++ni)
                acc[mi][ni] = __builtin_amdgcn_mfma_f32_16x16x32_bf16(
                    af[mi], bfr[ni], acc[mi][ni], 0, 0, 0);
    }

    // epilogue: C/D layout col=lane&15, row=(lane>>4)*4+reg (m89-verified)
    int em = emitted[b];
    float* outb = out + (size_t)b * LOO * OUTW + VV;
#pragma unroll
    for (int mi = 0; mi < 4; ++mi) {
        int rbase = brow + (wr << 6) + (mi << 4) + ((lane >> 4) << 2);
#pragma unroll
        for (int ni = 0; ni < 2; ++ni) {
            int col = bcol + (wc << 5) + (ni << 4) + (lane & 15);
            float badd = (col < em) ? 0.0f : -100.0f;
#pragma unroll
            for (int rr = 0; rr < 4; ++rr)
                outb[(size_t)(rbase + rr) * OUTW + col] = acc[mi][ni][rr] + badd;
        }
    }
}

extern "C" void kernel_launch(void* const* d_in, const int* in_sizes, int n_in,
                              void* d_out, int out_size, void* d_ws, size_t ws_size,
                              hipStream_t stream) {
    const float* h1   = (const float*)d_in[0];   // [8,1024,768]
    const float* h2   = (const float*)d_in[1];   // [8,1024,768]
    const float* lm   = (const float*)d_in[2];   // [8,1024,4096]
    const int*   tags = (const int*)d_in[3];     // [8,1024]
    float* out = (float*)d_out;                  // [8,1024,5120]

    // workspace: attn bf16 [8][256][768] + emitted[8]
    char* ws = (char*)d_ws;
    ushort_t* attn    = (ushort_t*)ws;                 // 3,145,728 B
    int*      emitted = (int*)(ws + 3145728);          // 32 B

    attn_fused_kernel<<<BB * EMAX, 256, 0, stream>>>(h1, tags, attn, emitted);
    mega_kernel<<<NGEMM + NCOPY, 256, 0, stream>>>(h2, attn, emitted, lm, out);
}

// Round 5
// 90.398 us; speedup vs baseline: 1.0707x; 1.0707x over previous
//
#include <hip/hip_runtime.h>
#include <hip/hip_bf16.h>
#include <stdint.h>

#define BB   8
#define LL   1024
#define LOO  1024
#define HH   768
#define VV   4096
#define OUTW 5120   // VV + LL
#define EMAX 256    // tags sorted from [0,256) => emitted <= 255

typedef unsigned short ushort_t;
typedef __attribute__((ext_vector_type(4))) float   f32x4;
typedef __attribute__((ext_vector_type(8))) __bf16  bf16x8;
typedef __attribute__((ext_vector_type(4))) float   float4v;
typedef __attribute__((ext_vector_type(4))) int     int4v;

static __device__ __forceinline__ ushort_t f2bf(float f) {
    union { float f; uint32_t u; } v; v.f = f;
    uint32_t u = v.u;
    uint32_t r = (u + 0x7fffu + ((u >> 16) & 1u)) >> 16;
    return (ushort_t)r;
}

// ---- K1: fused tag-scan + segment means -> bf16 attn [BB][EMAX][HH] ----
__global__ __launch_bounds__(256) void attn_fused_kernel(
        const float* __restrict__ h1,
        const int* __restrict__ tags,
        ushort_t* __restrict__ attn,
        int* __restrict__ emitted_out) {
    int b = blockIdx.x >> 8;
    int r = blockIdx.x & 255;
    int tid = threadIdx.x;

    __shared__ int stags[LL];        // 4 KB
    __shared__ int cnt[256];
    __shared__ int runpos[EMAX + 2];

    ((int4v*)stags)[tid] = ((const int4v*)(tags + b * LL))[tid];
    __syncthreads();

    int p0 = tid * 4;
    int st[4];
    int prevm1 = (p0 == 0) ? -2 : stags[p0 - 1];
    st[0] = (p0 == 0) || (stags[p0] != prevm1);
    st[1] = (stags[p0 + 1] != stags[p0]);
    st[2] = (stags[p0 + 2] != stags[p0 + 1]);
    st[3] = (stags[p0 + 3] != stags[p0 + 2]);
    int c = st[0] + st[1] + st[2] + st[3];
    cnt[tid] = c;
    __syncthreads();
    for (int off = 1; off < 256; off <<= 1) {
        int v = cnt[tid];
        int a = (tid >= off) ? cnt[tid - off] : 0;
        __syncthreads();
        cnt[tid] = v + a;
        __syncthreads();
    }
    int total = cnt[255];            // total runs (<= 256, tags sorted)
    int base = cnt[tid] - c;         // exclusive prefix
#pragma unroll
    for (int j = 0; j < 4; ++j)
        if (st[j]) runpos[base++] = p0 + j;
    if (tid == 0) runpos[total] = LL;
    __syncthreads();

    int em = total - 1;              // trailing open run dropped
    if (r == 0 && tid == 0) emitted_out[b] = em;

    ushort_t* arow = attn + ((size_t)b * EMAX + r) * HH;
    if (r >= em) {
        arow[tid] = 0; arow[tid + 256] = 0; arow[tid + 512] = 0;
        return;
    }
    int s = runpos[r], e = runpos[r + 1];
    float inv = 1.0f / (float)(e - s);
    const float* hb = h1 + (size_t)b * LL * HH;
    float a0 = 0.f, a1 = 0.f, a2 = 0.f;
    for (int p = s; p < e; ++p) {
        const float* row = hb + (size_t)p * HH;
        a0 += row[tid]; a1 += row[tid + 256]; a2 += row[tid + 512];
    }
    arow[tid]       = f2bf(a0 * inv);
    arow[tid + 256] = f2bf(a1 * inv);
    arow[tid + 512] = f2bf(a2 * inv);
}

// ---- K2: standalone LDS GEMM (R2-proven path) over out cols [VV,VV+256) ----
// C[b][o][l] = sum_h h2[b][o][h]*attn[b][l][h] + (l<em ? 0 : -100)
// 128 blocks: tile 128x128, BK=64, A staged f32 (cvt->bf16 on LDS read).
__global__ __launch_bounds__(256, 2) void gemm_kernel(
        const float* __restrict__ A,       // h2 f32 [BB][LOO][HH]
        const ushort_t* __restrict__ Bm,   // attn bf16 [BB][EMAX][HH]
        const int* __restrict__ emitted,
        float* __restrict__ out) {
    __shared__ char smem[49152];          // A f32 32KB @0, B bf16 16KB @32768

    int bid  = blockIdx.x;
    int b    = bid >> 4;
    int t2   = bid & 15;
    int brow = (t2 >> 1) << 7;            // 0..896
    int bcol = (t2 & 1) << 7;             // 0 or 128

    const int tid  = threadIdx.x;
    const int lane = tid & 63;
    const int wid  = tid >> 6;
    const int wr   = (wid >> 1) & 1;
    const int wc   = wid & 1;

    const float*    Ab = A  + (size_t)b * LOO * HH;
    const ushort_t* Bb = Bm + (size_t)b * EMAX * HH;

    f32x4 zero = {0.f, 0.f, 0.f, 0.f};
    f32x4 acc[4][4];
#pragma unroll
    for (int i = 0; i < 4; ++i)
#pragma unroll
        for (int j = 0; j < 4; ++j) acc[i][j] = zero;

    for (int k0 = 0; k0 < HH; k0 += 64) {
        __syncthreads();
#pragma unroll
        for (int i = 0; i < 8; ++i) {
            int off = i * 4096 + tid * 16;
            int row = off >> 8;                 // 256B per row (f32)
            int cb  = off & 255;
            int scb = cb ^ ((row & 7) << 5);
            const float* ga = Ab + (size_t)(brow + row) * HH + k0 + (scb >> 2);
            __builtin_amdgcn_global_load_lds(
                (const __attribute__((address_space(1))) void*)ga,
                (__attribute__((address_space(3))) void*)(smem + off), 16, 0, 0);
        }
#pragma unroll
        for (int i = 0; i < 4; ++i) {
            int off = i * 4096 + tid * 16;
            int row = off >> 7;                 // 128B per row (bf16)
            int cb  = off & 127;
            int scb = cb ^ ((row & 7) << 4);
            const ushort_t* gb = Bb + (size_t)(bcol + row) * HH + k0 + (scb >> 1);
            __builtin_amdgcn_global_load_lds(
                (const __attribute__((address_space(1))) void*)gb,
                (__attribute__((address_space(3))) void*)(smem + 32768 + off), 16, 0, 0);
        }
        asm volatile("s_waitcnt vmcnt(0)" ::: "memory");
        __syncthreads();

#pragma unroll
        for (int ks = 0; ks < 2; ++ks) {
            bf16x8 af[4], bfr[4];
#pragma unroll
            for (int mi = 0; mi < 4; ++mi) {
                int row  = (wr << 6) + (mi << 4) + (lane & 15);
                int colb = (ks << 7) + ((lane >> 4) << 5);        // f32 bytes
                int addr = (row << 8) + (colb ^ ((row & 7) << 5));
                f32x4 a0 = *(const f32x4*)(smem + addr);
                f32x4 a1 = *(const f32x4*)(smem + addr + 16);
                bf16x8 t;
                t[0] = (__bf16)a0[0]; t[1] = (__bf16)a0[1];
                t[2] = (__bf16)a0[2]; t[3] = (__bf16)a0[3];
                t[4] = (__bf16)a1[0]; t[5] = (__bf16)a1[1];
                t[6] = (__bf16)a1[2]; t[7] = (__bf16)a1[3];
                af[mi] = t;
            }
#pragma unroll
            for (int ni = 0; ni < 4; ++ni) {
                int row  = (wc << 6) + (ni << 4) + (lane & 15);
                int colb = (ks << 6) + ((lane >> 4) << 4);        // bf16 bytes
                int addr = (row << 7) + (colb ^ ((row & 7) << 4));
                bfr[ni] = *(const bf16x8*)(smem + 32768 + addr);
            }
#pragma unroll
            for (int mi = 0; mi < 4; ++mi)
#pragma unroll
                for (int ni = 0; ni < 4; ++ni)
                    acc[mi][ni] = __builtin_amdgcn_mfma_f32_16x16x32_bf16(
                        af[mi], bfr[ni], acc[mi][ni], 0, 0, 0);
        }
    }

    int em = emitted[b];
    float* outb = out + (size_t)b * LOO * OUTW + VV;
#pragma unroll
    for (int mi = 0; mi < 4; ++mi) {
        int rbase = brow + (wr << 6) + (mi << 4) + ((lane >> 4) << 2);
#pragma unroll
        for (int ni = 0; ni < 4; ++ni) {
            int col = bcol + (wc << 6) + (ni << 4) + (lane & 15);
            float badd = (col < em) ? 0.0f : -100.0f;
#pragma unroll
            for (int rr = 0; rr < 4; ++rr)
                outb[(size_t)(rbase + rr) * OUTW + col] = acc[mi][ni][rr] + badd;
        }
    }
}

// ---- K3: solo streaming copy+fill with non-temporal hints ----
// copy lm -> out[:,:,0:VV]; fill out[:,:,VV+256..VV+LL) with -100.
__global__ __launch_bounds__(256) void copy_fill_kernel(
        const float* __restrict__ lm,
        float* __restrict__ out) {
    const float4v* in4 = (const float4v*)lm;
    float4v* out4 = (float4v*)out;
    int c = blockIdx.x * 256 + threadIdx.x;        // 0..524287

    // fill first: independent stores, retire under load latency
    float4v fv = {-100.f, -100.f, -100.f, -100.f};
#pragma unroll
    for (int j = 0; j < 3; ++j) {
        int idx = j * 524288 + c;                  // 0..1572863
        int row = idx / 192;                       // 8192 rows x 192 float4
        int col = idx - row * 192;
        __builtin_nontemporal_store(fv, &out4[(size_t)row * (OUTW / 4) + (VV + 256) / 4 + col]);
    }

    // copy: 16 stripes of 8MB, 4 loads in flight per group
#pragma unroll
    for (int g = 0; g < 4; ++g) {
        size_t i0 = ((size_t)(g * 4 + 0) << 19) + c;
        size_t i1 = ((size_t)(g * 4 + 1) << 19) + c;
        size_t i2 = ((size_t)(g * 4 + 2) << 19) + c;
        size_t i3 = ((size_t)(g * 4 + 3) << 19) + c;
        float4v v0 = __builtin_nontemporal_load(&in4[i0]);
        float4v v1 = __builtin_nontemporal_load(&in4[i1]);
        float4v v2 = __builtin_nontemporal_load(&in4[i2]);
        float4v v3 = __builtin_nontemporal_load(&in4[i3]);
        __builtin_nontemporal_store(v0, &out4[i0 + ((i0 >> 10) << 8)]);
        __builtin_nontemporal_store(v1, &out4[i1 + ((i1 >> 10) << 8)]);
        __builtin_nontemporal_store(v2, &out4[i2 + ((i2 >> 10) << 8)]);
        __builtin_nontemporal_store(v3, &out4[i3 + ((i3 >> 10) << 8)]);
    }
}

extern "C" void kernel_launch(void* const* d_in, const int* in_sizes, int n_in,
                              void* d_out, int out_size, void* d_ws, size_t ws_size,
                              hipStream_t stream) {
    const float* h1   = (const float*)d_in[0];   // [8,1024,768]
    const float* h2   = (const float*)d_in[1];   // [8,1024,768]
    const float* lm   = (const float*)d_in[2];   // [8,1024,4096]
    const int*   tags = (const int*)d_in[3];     // [8,1024]
    float* out = (float*)d_out;                  // [8,1024,5120]

    // workspace: attn bf16 [8][256][768] + emitted[8]
    char* ws = (char*)d_ws;
    ushort_t* attn    = (ushort_t*)ws;                 // 3,145,728 B
    int*      emitted = (int*)(ws + 3145728);          // 32 B

    attn_fused_kernel<<<BB * EMAX, 256, 0, stream>>>(h1, tags, attn, emitted);
    gemm_kernel<<<128, 256, 0, stream>>>(h2, attn, emitted, out);
    copy_fill_kernel<<<2048, 256, 0, stream>>>(lm, out);
}

// Round 6
// 86.322 us; speedup vs baseline: 1.1212x; 1.0472x over previous
//
#include <hip/hip_runtime.h>
#include <hip/hip_bf16.h>
#include <stdint.h>

#define BB   8
#define LL   1024
#define LOO  1024
#define HH   768
#define VV   4096
#define OUTW 5120   // VV + LL
#define EMAX 256    // tags sorted from [0,256) => emitted <= 255

typedef unsigned short ushort_t;
typedef __attribute__((ext_vector_type(4))) float   f32x4;
typedef __attribute__((ext_vector_type(8))) __bf16  bf16x8;
typedef __attribute__((ext_vector_type(4))) float   float4v;
typedef __attribute__((ext_vector_type(4))) int     int4v;
typedef __attribute__((ext_vector_type(4))) unsigned short ushort4v;

static __device__ __forceinline__ ushort_t f2bf(float f) {
    union { float f; uint32_t u; } v; v.f = f;
    uint32_t u = v.u;
    uint32_t r = (u + 0x7fffu + ((u >> 16) & 1u)) >> 16;
    return (ushort_t)r;
}

// ---- K1: fused tag-scan + segment means -> bf16 attn [BB][EMAX][HH] ----
__global__ __launch_bounds__(256) void attn_fused_kernel(
        const float* __restrict__ h1,
        const int* __restrict__ tags,
        ushort_t* __restrict__ attn,
        int* __restrict__ emitted_out) {
    int b = blockIdx.x >> 8;
    int r = blockIdx.x & 255;
    int tid = threadIdx.x;

    __shared__ int stags[LL];        // 4 KB
    __shared__ int cnt[256];
    __shared__ int runpos[EMAX + 2];

    ((int4v*)stags)[tid] = ((const int4v*)(tags + b * LL))[tid];
    __syncthreads();

    int p0 = tid * 4;
    int st[4];
    int prevm1 = (p0 == 0) ? -2 : stags[p0 - 1];
    st[0] = (p0 == 0) || (stags[p0] != prevm1);
    st[1] = (stags[p0 + 1] != stags[p0]);
    st[2] = (stags[p0 + 2] != stags[p0 + 1]);
    st[3] = (stags[p0 + 3] != stags[p0 + 2]);
    int c = st[0] + st[1] + st[2] + st[3];
    cnt[tid] = c;
    __syncthreads();
    for (int off = 1; off < 256; off <<= 1) {
        int v = cnt[tid];
        int a = (tid >= off) ? cnt[tid - off] : 0;
        __syncthreads();
        cnt[tid] = v + a;
        __syncthreads();
    }
    int total = cnt[255];            // total runs (<= 256, tags sorted)
    int base = cnt[tid] - c;         // exclusive prefix
#pragma unroll
    for (int j = 0; j < 4; ++j)
        if (st[j]) runpos[base++] = p0 + j;
    if (tid == 0) runpos[total] = LL;
    __syncthreads();

    int em = total - 1;              // trailing open run dropped
    if (r == 0 && tid == 0) emitted_out[b] = em;

    ushort_t* arow = attn + ((size_t)b * EMAX + r) * HH;
    if (r >= em) {
        arow[tid] = 0; arow[tid + 256] = 0; arow[tid + 512] = 0;
        return;
    }
    int s = runpos[r], e = runpos[r + 1];
    float inv = 1.0f / (float)(e - s);
    const float* hb = h1 + (size_t)b * LL * HH;
    float a0 = 0.f, a1 = 0.f, a2 = 0.f;
    for (int p = s; p < e; ++p) {
        const float* row = hb + (size_t)p * HH;
        a0 += row[tid]; a1 += row[tid + 256]; a2 += row[tid + 512];
    }
    arow[tid]       = f2bf(a0 * inv);
    arow[tid + 256] = f2bf(a1 * inv);
    arow[tid + 512] = f2bf(a2 * inv);
}

// ---- K2: output-centric fused kernel. Each block owns 16 out rows: ----
//  (a) GEMM slab 16x256x768: out[:, VV..VV+256) = h2 @ attn^T + bias
//  (b) copy lm -> out[:, 0..VV)  (non-temporal)
//  (c) fill out[:, VV+256..VV+LL) with -100
// 512 blocks x 256 thr, LDS 34 KB -> 4 blocks/CU, all blocks resident.
__global__ __launch_bounds__(256, 4) void fused_out_kernel(
        const float* __restrict__ h2,      // f32 [BB][LOO][HH]
        const ushort_t* __restrict__ Bm,   // attn bf16 [BB][EMAX][HH]
        const int* __restrict__ emitted,
        const float* __restrict__ lm,
        float* __restrict__ out) {
    __shared__ char smem[34816];   // A bf16 [16][64] 2KB @0, B bf16 [256][64] 32KB @2048

    const int bid = blockIdx.x;
    const int b   = bid >> 6;            // 64 blocks per batch
    const int r0  = (bid & 63) << 4;     // first of 16 rows

    const int tid  = threadIdx.x;
    const int lane = tid & 63;
    const int w    = tid >> 6;           // wave 0..3 -> N-quarter

    const float*    Ab = h2 + ((size_t)b * LOO + r0) * HH;
    const ushort_t* Bb = Bm + (size_t)b * EMAX * HH;

    f32x4 zero = {0.f, 0.f, 0.f, 0.f};
    f32x4 acc[4];
    acc[0] = zero; acc[1] = zero; acc[2] = zero; acc[3] = zero;

    // -------- GEMM phase: 12 K-chunks of 64 --------
    const int arow_s = tid >> 4;         // staging row 0..15
    const int akq    = tid & 15;         // staging k-quad
    for (int k0 = 0; k0 < HH; k0 += 64) {
        __syncthreads();
        // stage A: 16x64 f32 -> bf16 LDS, reg-staged, XOR-swizzled write
        {
            f32x4 v = *(const f32x4*)(Ab + (size_t)arow_s * HH + k0 + akq * 4);
            ushort4v o;
            o[0] = f2bf(v[0]); o[1] = f2bf(v[1]); o[2] = f2bf(v[2]); o[3] = f2bf(v[3]);
            *(ushort4v*)(smem + arow_s * 128 + ((akq * 8) ^ ((arow_s & 7) << 4))) = o;
        }
        // stage B: 256x64 bf16 via global_load_lds (linear dest, pre-swizzled src)
#pragma unroll
        for (int i = 0; i < 8; ++i) {
            int off = i * 4096 + tid * 16;
            int row = off >> 7;               // 128B per row
            int cb  = off & 127;
            int scb = cb ^ ((row & 7) << 4);
            const ushort_t* gb = Bb + (size_t)row * HH + k0 + (scb >> 1);
            __builtin_amdgcn_global_load_lds(
                (const __attribute__((address_space(1))) void*)gb,
                (__attribute__((address_space(3))) void*)(smem + 2048 + off), 16, 0, 0);
        }
        asm volatile("s_waitcnt vmcnt(0)" ::: "memory");
        __syncthreads();

#pragma unroll
        for (int ks = 0; ks < 2; ++ks) {
            int kb   = (ks << 6) + ((lane >> 4) << 4);       // byte offset in 128B row
            int ar   = lane & 15;
            bf16x8 af = *(const bf16x8*)(smem + ar * 128 + (kb ^ ((ar & 7) << 4)));
#pragma unroll
            for (int ni = 0; ni < 4; ++ni) {
                int br = ((w << 2) + ni) * 16 + (lane & 15);
                bf16x8 bf = *(const bf16x8*)(smem + 2048 + br * 128 + (kb ^ ((br & 7) << 4)));
                acc[ni] = __builtin_amdgcn_mfma_f32_16x16x32_bf16(af, bf, acc[ni], 0, 0, 0);
            }
        }
    }

    // GEMM epilogue: C/D layout col=lane&15, row=(lane>>4)*4+reg
    {
        int em = emitted[b];
        float* outb = out + ((size_t)b * LOO + r0) * OUTW + VV;
#pragma unroll
        for (int ni = 0; ni < 4; ++ni) {
            int l = ((w << 2) + ni) * 16 + (lane & 15);
            float badd = (l < em) ? 0.0f : -100.0f;
            int rbase = (lane >> 4) << 2;
#pragma unroll
            for (int rr = 0; rr < 4; ++rr)
                outb[(size_t)(rbase + rr) * OUTW + l] = acc[ni][rr] + badd;
        }
    }

    // -------- copy + fill phase (non-temporal both ways) --------
    const float4v* lm4 = (const float4v*)lm + ((size_t)b * LOO + r0) * (VV / 4);
    float4v* o4 = (float4v*)out + ((size_t)b * LOO + r0) * (OUTW / 4);
    float4v fv = {-100.f, -100.f, -100.f, -100.f};
#pragma unroll 2
    for (int r = 0; r < 16; ++r) {
        float4v v0 = __builtin_nontemporal_load(&lm4[r * 1024 + tid]);
        float4v v1 = __builtin_nontemporal_load(&lm4[r * 1024 + tid + 256]);
        float4v v2 = __builtin_nontemporal_load(&lm4[r * 1024 + tid + 512]);
        float4v v3 = __builtin_nontemporal_load(&lm4[r * 1024 + tid + 768]);
        __builtin_nontemporal_store(v0, &o4[r * 1280 + tid]);
        __builtin_nontemporal_store(v1, &o4[r * 1280 + tid + 256]);
        __builtin_nontemporal_store(v2, &o4[r * 1280 + tid + 512]);
        __builtin_nontemporal_store(v3, &o4[r * 1280 + tid + 768]);
        if (tid < 192)
            __builtin_nontemporal_store(fv, &o4[r * 1280 + 1088 + tid]);
    }
}

extern "C" void kernel_launch(void* const* d_in, const int* in_sizes, int n_in,
                              void* d_out, int out_size, void* d_ws, size_t ws_size,
                              hipStream_t stream) {
    const float* h1   = (const float*)d_in[0];   // [8,1024,768]
    const float* h2   = (const float*)d_in[1];   // [8,1024,768]
    const float* lm   = (const float*)d_in[2];   // [8,1024,4096]
    const int*   tags = (const int*)d_in[3];     // [8,1024]
    float* out = (float*)d_out;                  // [8,1024,5120]

    // workspace: attn bf16 [8][256][768] + emitted[8]
    char* ws = (char*)d_ws;
    ushort_t* attn    = (ushort_t*)ws;                 // 3,145,728 B
    int*      emitted = (int*)(ws + 3145728);          // 32 B

    attn_fused_kernel<<<BB * EMAX, 256, 0, stream>>>(h1, tags, attn, emitted);
    fused_out_kernel<<<512, 256, 0, stream>>>(h2, attn, emitted, lm, out);
}